// Round 1
// baseline (108000.208 us; speedup 1.0000x reference)
//
#include <hip/hip_runtime.h>

#define NB 64
#define NNODE 1085
#define HIST 24
#define PRED 24
#define KHOP 3
#define HDIM 64
#define FXD 1
#define FMD 11
#define FD 12
#define NE 17360
#define NROWS (NB*NNODE)   // 69440

typedef float v4 __attribute__((ext_vector_type(4)));

__device__ __forceinline__ float sigm(float x){ return 1.0f/(1.0f + __expf(-x)); }
__device__ __forceinline__ float tanh_f(float x){ return 1.0f - 2.0f/(__expf(2.0f*x)+1.0f); }

// Build xn = concat([x_scalar, feat11]) for all rows; also init hop-1 residual buffer.
__global__ void build_xn_k(const float* __restrict__ xsrc, long xs_bs, long xs_off,
                           const float* __restrict__ feat, long f_bs, long f_off,
                           float* __restrict__ xn, float* __restrict__ out1)
{
    int row = blockIdx.x*256 + threadIdx.x;
    if (row >= NROWS) return;
    int b = row / NNODE, n = row - b*NNODE;
    float v[12];
    v[0] = xsrc[(long)b*xs_bs + xs_off + n];
    const float* fp = feat + (long)b*f_bs + f_off + (long)n*FMD;
    #pragma unroll
    for (int i=0;i<FMD;i++) v[1+i] = fp[i];
    v4* xp = (v4*)(xn  + (long)row*FD);
    v4* op = (v4*)(out1 + (long)row*FD);
    #pragma unroll
    for (int q=0;q<3;q++){
        v4 t; t[0]=v[4*q]; t[1]=v[4*q+1]; t[2]=v[4*q+2]; t[3]=v[4*q+3];
        xp[q]=t; op[q]=t;
    }
}

// Edge MLP + atomic scatter-add.  out must be pre-initialized with x (residual).
// 2 edges per thread: edges e and e+NE/2 of batch b.
__global__ __launch_bounds__(256) void gnn_edge_k(const float* __restrict__ x,
    const float* __restrict__ We, const float* __restrict__ be,
    const int* __restrict__ src, const int* __restrict__ dst,
    float* __restrict__ out)
{
    __shared__ __align__(16) float w_s[288];   // We row-major (24,12)
    __shared__ float be_s[12];
    int t = threadIdx.x;
    for (int i=t;i<288;i+=256) w_s[i]=We[i];
    if (t<12) be_s[t]=be[t];
    __syncthreads();

    int idx = blockIdx.x*256 + t;            // < NB*NE/2
    const int half = NE/2;
    int e0 = idx % half, b = idx / half;

    float xc[2][24];
    int dsts[2];
    #pragma unroll
    for (int p=0;p<2;p++){
        int e = e0 + p*half;
        int s = src[e]; int d = dst[e]; dsts[p]=d;
        const v4* xs = (const v4*)(x + ((long)b*NNODE + s)*FD);
        const v4* xd = (const v4*)(x + ((long)b*NNODE + d)*FD);
        #pragma unroll
        for (int q=0;q<3;q++){
            v4 a = xs[q]; v4 c = xd[q];
            #pragma unroll
            for (int j=0;j<4;j++){ xc[p][4*q+j]=a[j]; xc[p][12+4*q+j]=c[j]; }
        }
    }
    float acc[2][12];
    #pragma unroll
    for (int p=0;p<2;p++)
        #pragma unroll
        for (int f2=0;f2<12;f2++) acc[p][f2]=be_s[f2];
    #pragma unroll 6
    for (int i=0;i<24;i++){
        v4 w0=*(const v4*)&w_s[i*12];
        v4 w1=*(const v4*)&w_s[i*12+4];
        v4 w2=*(const v4*)&w_s[i*12+8];
        #pragma unroll
        for (int p=0;p<2;p++){
            float xv=xc[p][i];
            #pragma unroll
            for (int j=0;j<4;j++){
                acc[p][j]    += xv*w0[j];
                acc[p][4+j]  += xv*w1[j];
                acc[p][8+j]  += xv*w2[j];
            }
        }
    }
    #pragma unroll
    for (int p=0;p<2;p++){
        float* ob = out + ((long)b*NNODE + dsts[p])*FD;
        #pragma unroll
        for (int f2=0;f2<12;f2++) atomicAdd(ob+f2, fmaxf(acc[p][f2],0.0f));
    }
}

// Fused GRU: C = [xg|xn|h] @ [Wx;Wh] (K=88, N=192) + gate nonlinearity, h updated in place.
// Also copies xg into out_next (residual init for next gnn hop).
#define KC 44
__global__ __launch_bounds__(256) void gru_k(const float* __restrict__ xg, const float* __restrict__ xn,
    float* __restrict__ h, const float* __restrict__ Wx, const float* __restrict__ Wh,
    const float* __restrict__ bx, const float* __restrict__ bh, float* __restrict__ out_next)
{
    __shared__ __align__(16) float A_s[KC][64];
    __shared__ __align__(16) float W_s[KC][192];
    const int tid = threadIdx.x;
    const int tx = tid & 15, ty = tid >> 4;   // tx: 16 col-groups (j=tx*4..+3), ty: 16 row-groups
    const long row0 = (long)blockIdx.x * 64;

    float acc_r[16], acc_z[16], acc_gn[16], acc_ghn[16];
    #pragma unroll
    for (int i=0;i<16;i++){ acc_r[i]=0.f; acc_z[i]=0.f; acc_gn[i]=0.f; acc_ghn[i]=0.f; }

    // ---------------- chunk 0: k = 0..43 ----------------
    for (int i=tid; i<KC*192; i+=256){
        int kk = i/192, c = i - kk*192;
        W_s[kk][c] = (kk<24) ? Wx[kk*192+c] : Wh[(kk-24)*192+c];
    }
    for (int i=tid; i<KC*64; i+=256){
        int kk = i>>6, r = i&63;
        long row = row0 + r;
        float v;
        if (kk<12){ v = xg[row*FD+kk]; if (out_next) out_next[row*FD+kk]=v; }
        else if (kk<24) v = xn[row*FD+(kk-12)];
        else v = h[row*HDIM + (kk-24)];
        A_s[kk][r]=v;
    }
    __syncthreads();
    #pragma unroll 4
    for (int kk=0;kk<24;kk++){
        v4 av=*(const v4*)&A_s[kk][ty*4];
        v4 wr=*(const v4*)&W_s[kk][tx*4];
        v4 wz=*(const v4*)&W_s[kk][64+tx*4];
        v4 wn=*(const v4*)&W_s[kk][128+tx*4];
        #pragma unroll
        for (int dr=0;dr<4;dr++)
            #pragma unroll
            for (int dc=0;dc<4;dc++){
                acc_r[dr*4+dc]+=av[dr]*wr[dc];
                acc_z[dr*4+dc]+=av[dr]*wz[dc];
                acc_gn[dr*4+dc]+=av[dr]*wn[dc];
            }
    }
    #pragma unroll 4
    for (int kk=24;kk<44;kk++){
        v4 av=*(const v4*)&A_s[kk][ty*4];
        v4 wr=*(const v4*)&W_s[kk][tx*4];
        v4 wz=*(const v4*)&W_s[kk][64+tx*4];
        v4 wn=*(const v4*)&W_s[kk][128+tx*4];
        #pragma unroll
        for (int dr=0;dr<4;dr++)
            #pragma unroll
            for (int dc=0;dc<4;dc++){
                acc_r[dr*4+dc]+=av[dr]*wr[dc];
                acc_z[dr*4+dc]+=av[dr]*wz[dc];
                acc_ghn[dr*4+dc]+=av[dr]*wn[dc];
            }
    }
    __syncthreads();
    // ---------------- chunk 1: k = 44..87 (Wh rows 20..63, h cols 20..63) ----------------
    for (int i=tid; i<KC*192; i+=256){
        int kk = i/192, c = i - kk*192;
        W_s[kk][c] = Wh[(20+kk)*192+c];
    }
    for (int i=tid; i<KC*64; i+=256){
        int kk = i>>6, r = i&63;
        A_s[kk][r] = h[(row0+r)*HDIM + 20 + kk];
    }
    __syncthreads();
    #pragma unroll 4
    for (int kk=0;kk<44;kk++){
        v4 av=*(const v4*)&A_s[kk][ty*4];
        v4 wr=*(const v4*)&W_s[kk][tx*4];
        v4 wz=*(const v4*)&W_s[kk][64+tx*4];
        v4 wn=*(const v4*)&W_s[kk][128+tx*4];
        #pragma unroll
        for (int dr=0;dr<4;dr++)
            #pragma unroll
            for (int dc=0;dc<4;dc++){
                acc_r[dr*4+dc]+=av[dr]*wr[dc];
                acc_z[dr*4+dc]+=av[dr]*wz[dc];
                acc_ghn[dr*4+dc]+=av[dr]*wn[dc];
            }
    }

    // ---------------- epilogue ----------------
    v4 bxr=*(const v4*)&bx[tx*4],     bhr=*(const v4*)&bh[tx*4];
    v4 bxz=*(const v4*)&bx[64+tx*4],  bhz=*(const v4*)&bh[64+tx*4];
    v4 bxn=*(const v4*)&bx[128+tx*4], bhn=*(const v4*)&bh[128+tx*4];
    #pragma unroll
    for (int dr=0;dr<4;dr++){
        long row = row0 + ty*4 + dr;
        v4 hold = *(const v4*)&h[row*HDIM + tx*4];
        v4 hnew;
        #pragma unroll
        for (int dc=0;dc<4;dc++){
            float rr = sigm(acc_r[dr*4+dc] + bxr[dc] + bhr[dc]);
            float zz = sigm(acc_z[dr*4+dc] + bxz[dc] + bhz[dc]);
            float nn = tanh_f(acc_gn[dr*4+dc] + bxn[dc] + rr*(acc_ghn[dr*4+dc] + bhn[dc]));
            hnew[dc] = (1.0f-zz)*nn + zz*hold[dc];
        }
        *(v4*)&h[row*HDIM + tx*4] = hnew;
    }
}

// fc: x_new = [h0|h1|h2] @ fc_w + fc_b, written to x_cur and the output slice p.
__global__ void fc_k(const float* __restrict__ h, const float* __restrict__ fc_w,
                     const float* __restrict__ fc_b, float* __restrict__ x_cur,
                     float* __restrict__ out, int p)
{
    int row = blockIdx.x*256+threadIdx.x;
    if (row>=NROWS) return;
    float acc = fc_b[0];
    #pragma unroll
    for (int k=0;k<3;k++){
        const float* hb = h + (long)k*NROWS*HDIM + (long)row*HDIM;
        const float* wb = fc_w + k*HDIM;
        #pragma unroll
        for (int q=0;q<16;q++){
            v4 hv=*(const v4*)&hb[q*4];
            v4 wv=*(const v4*)&wb[q*4];
            acc += hv[0]*wv[0]+hv[1]*wv[1]+hv[2]*wv[2]+hv[3]*wv[3];
        }
    }
    x_cur[row]=acc;
    int b=row/NNODE, n=row-b*NNODE;
    out[((long)b*PRED + p)*NNODE + n] = acc;
}

extern "C" void kernel_launch(void* const* d_in, const int* in_sizes, int n_in,
                              void* d_out, int out_size, void* d_ws, size_t ws_size,
                              hipStream_t stream)
{
    const float* x_hist   = (const float*)d_in[0];
    const float* enc_misc = (const float*)d_in[1];
    const float* dec      = (const float*)d_in[2];
    const float* We       = (const float*)d_in[3];
    const float* be       = (const float*)d_in[4];
    const float* Wx       = (const float*)d_in[5];
    const float* Wh       = (const float*)d_in[6];
    const float* bx       = (const float*)d_in[7];
    const float* bh       = (const float*)d_in[8];
    const float* fc_w     = (const float*)d_in[9];
    const float* fc_b     = (const float*)d_in[10];
    const int*   src      = (const int*)d_in[11];
    const int*   dst      = (const int*)d_in[12];
    float* out = (float*)d_out;

    // workspace layout (~67 MB)
    float* h    = (float*)d_ws;                         // 3 * NROWS * HDIM
    float* xn   = h  + (size_t)3*NROWS*HDIM;            // NROWS*12
    float* xg1  = xn + (size_t)NROWS*FD;
    float* xg2  = xg1 + (size_t)NROWS*FD;
    float* xg3  = xg2 + (size_t)NROWS*FD;
    float* x_cur= xg3 + (size_t)NROWS*FD;               // NROWS

    hipMemsetAsync(h, 0, (size_t)3*NROWS*HDIM*sizeof(float), stream);

    const int gRow  = (NROWS+255)/256;     // 272
    const int gEdge = NB*NE/2/256;         // 2170
    const int gGru  = NROWS/64;            // 1085

    auto step = [&](const float* xsrc, long xs_bs, long xs_off,
                    const float* feat, long f_bs, long f_off){
        build_xn_k<<<gRow,256,0,stream>>>(xsrc,xs_bs,xs_off,feat,f_bs,f_off,xn,xg1);
        gnn_edge_k<<<gEdge,256,0,stream>>>(xn, We,be,src,dst, xg1);
        gru_k<<<gGru,256,0,stream>>>(xg1,xn,h,                    Wx,          Wh,          bx,      bh,      xg2);
        gnn_edge_k<<<gEdge,256,0,stream>>>(xg1,We,be,src,dst, xg2);
        gru_k<<<gGru,256,0,stream>>>(xg2,xn,h+(size_t)NROWS*HDIM,  Wx+24*192,   Wh+64*192,   bx+192,  bh+192,  xg3);
        gnn_edge_k<<<gEdge,256,0,stream>>>(xg2,We,be,src,dst, xg3);
        gru_k<<<gGru,256,0,stream>>>(xg3,xn,h+(size_t)2*NROWS*HDIM,Wx+2*24*192, Wh+2*64*192, bx+2*192,bh+2*192,nullptr);
    };

    // history: t = 0..22, features slice t+1 (all from enc_misc)
    for (int t=0;t<HIST-1;t++)
        step(x_hist,(long)HIST*NNODE,(long)t*NNODE,
             enc_misc,(long)HIST*NNODE*FMD,(long)(t+1)*NNODE*FMD);

    // prediction: p = 0..23, features = dec[:,p]; x feedback via x_cur
    for (int p=0;p<PRED;p++){
        if (p==0)
            step(x_hist,(long)HIST*NNODE,(long)(HIST-1)*NNODE,
                 dec,(long)PRED*NNODE*FMD,(long)p*NNODE*FMD);
        else
            step(x_cur,(long)NNODE,0L,
                 dec,(long)PRED*NNODE*FMD,(long)p*NNODE*FMD);
        fc_k<<<gRow,256,0,stream>>>(h, fc_w, fc_b, x_cur, out, p);
    }
}

// Round 2
// 22770.110 us; speedup vs baseline: 4.7431x; 4.7431x over previous
//
#include <hip/hip_runtime.h>

#define NB 64
#define NNODE 1085
#define HIST 24
#define PRED 24
#define KHOP 3
#define HDIM 64
#define FXD 1
#define FMD 11
#define FD 12
#define NE 17360
#define NROWS (NB*NNODE)   // 69440
#define CHUNK 136          // nodes per gather chunk (8 chunks cover 1085)

typedef float v4 __attribute__((ext_vector_type(4)));

__device__ __forceinline__ float sigm(float x){ return 1.0f/(1.0f + __expf(-x)); }
__device__ __forceinline__ float tanh_f(float x){ return 1.0f - 2.0f/(__expf(2.0f*x)+1.0f); }

// ---------------- CSR build (once per launch) ----------------
__global__ void csr_count_k(const int* __restrict__ dst, int* __restrict__ deg)
{
    int e = blockIdx.x*256 + threadIdx.x;
    if (e < NE) atomicAdd(&deg[dst[e]], 1);
}

__global__ __launch_bounds__(1024) void csr_scan_k(const int* __restrict__ deg,
                                                   int* __restrict__ offs, int* __restrict__ curs)
{
    __shared__ int s[2][2048];
    int t = threadIdx.x;
    for (int i=t;i<2048;i+=1024) s[0][i] = (i<NNODE) ? deg[i] : 0;
    __syncthreads();
    int cur = 0;
    for (int d=1; d<2048; d<<=1){
        for (int i=t;i<2048;i+=1024){
            int v = s[cur][i];
            if (i>=d) v += s[cur][i-d];
            s[cur^1][i] = v;
        }
        __syncthreads();
        cur ^= 1;
    }
    for (int i=t;i<=NNODE;i+=1024){
        int v = (i==0) ? 0 : s[cur][i-1];
        offs[i] = v;
        if (i<NNODE) curs[i] = v;
    }
}

__global__ void csr_fill_k(const int* __restrict__ dst, int* __restrict__ curs,
                           int* __restrict__ elist)
{
    int e = blockIdx.x*256 + threadIdx.x;
    if (e < NE){
        int d = dst[e];
        int p = atomicAdd(&curs[d], 1);
        elist[p] = e;
    }
}

// ---------------- build xn = concat([x_scalar, feat11]) ----------------
__global__ void build_xn_k(const float* __restrict__ xsrc, long xs_bs, long xs_off,
                           const float* __restrict__ feat, long f_bs, long f_off,
                           float* __restrict__ xn)
{
    int row = blockIdx.x*256 + threadIdx.x;
    if (row >= NROWS) return;
    int b = row / NNODE, n = row - b*NNODE;
    float v[12];
    v[0] = xsrc[(long)b*xs_bs + xs_off + n];
    const float* fp = feat + (long)b*f_bs + f_off + (long)n*FMD;
    #pragma unroll
    for (int i=0;i<FMD;i++) v[1+i] = fp[i];
    v4* xp = (v4*)(xn + (long)row*FD);
    #pragma unroll
    for (int q=0;q<3;q++){
        v4 tq; tq[0]=v[4*q]; tq[1]=v[4*q+1]; tq[2]=v[4*q+2]; tq[3]=v[4*q+3];
        xp[q]=tq;
    }
}

// ---------------- GNN hop: CSR gather, LDS-accumulated, residual fused ----------------
// block: one (batch, node-chunk); stages x[b] fully in LDS; edge-parallel MLP;
// ds_add_f32 accumulation; out = x + acc.
__global__ __launch_bounds__(256) void gnn_gather_k(const float* __restrict__ x,
    const float* __restrict__ We, const float* __restrict__ be,
    const int* __restrict__ src, const int* __restrict__ dst,
    const int* __restrict__ elist, const int* __restrict__ offs,
    float* __restrict__ out)
{
    __shared__ __align__(16) float x_s[NNODE*FD];    // 52080 B
    __shared__ __align__(16) float acc_s[CHUNK*FD];  // 6528 B
    __shared__ __align__(16) float w_s[288];
    __shared__ float be_s[12];
    const int t = threadIdx.x;
    const int b = blockIdx.x >> 3, c = blockIdx.x & 7;
    const int n0 = c*CHUNK, n1 = min(NNODE, n0+CHUNK);

    const v4* xg4 = (const v4*)(x + (long)b*NNODE*FD);
    for (int i=t; i<NNODE*FD/4; i+=256) ((v4*)x_s)[i] = xg4[i];
    for (int i=t; i<288; i+=256) w_s[i]=We[i];
    if (t<12) be_s[t]=be[t];
    for (int i=t; i<(n1-n0)*FD; i+=256) acc_s[i]=0.f;
    __syncthreads();

    const int e_beg = offs[n0], e_end = offs[n1];
    for (int idx=e_beg+t; idx<e_end; idx+=256){
        int e = elist[idx];
        int sN = src[e], dN = dst[e];
        float cin[24];
        const v4* xsv = (const v4*)&x_s[sN*FD];
        const v4* xdv = (const v4*)&x_s[dN*FD];
        #pragma unroll
        for (int q=0;q<3;q++){
            v4 a = xsv[q]; v4 cc = xdv[q];
            #pragma unroll
            for (int j=0;j<4;j++){ cin[4*q+j]=a[j]; cin[12+4*q+j]=cc[j]; }
        }
        float acc[12];
        #pragma unroll
        for (int f=0;f<12;f++) acc[f]=be_s[f];
        #pragma unroll 6
        for (int i=0;i<24;i++){
            float xv = cin[i];
            v4 w0=*(const v4*)&w_s[i*12];
            v4 w1=*(const v4*)&w_s[i*12+4];
            v4 w2=*(const v4*)&w_s[i*12+8];
            #pragma unroll
            for (int j=0;j<4;j++){
                acc[j]   += xv*w0[j];
                acc[4+j] += xv*w1[j];
                acc[8+j] += xv*w2[j];
            }
        }
        float* ab = &acc_s[(dN-n0)*FD];
        #pragma unroll
        for (int f=0;f<12;f++) atomicAdd(&ab[f], fmaxf(acc[f],0.f));
    }
    __syncthreads();

    const int cnt4 = (n1-n0)*FD/4;
    const v4* xs4 = (const v4*)&x_s[n0*FD];
    const v4* ac4 = (const v4*)acc_s;
    v4* ob4 = (v4*)(out + ((long)b*NNODE + n0)*FD);
    for (int i=t; i<cnt4; i+=256) ob4[i] = xs4[i] + ac4[i];
}

// ---------------- Fused GRU (unchanged structure) ----------------
#define KC 44
__global__ __launch_bounds__(256) void gru_k(const float* __restrict__ xg, const float* __restrict__ xn,
    float* __restrict__ h, const float* __restrict__ Wx, const float* __restrict__ Wh,
    const float* __restrict__ bx, const float* __restrict__ bh)
{
    __shared__ __align__(16) float A_s[KC][64];
    __shared__ __align__(16) float W_s[KC][192];
    const int tid = threadIdx.x;
    const int tx = tid & 15, ty = tid >> 4;
    const long row0 = (long)blockIdx.x * 64;

    float acc_r[16], acc_z[16], acc_gn[16], acc_ghn[16];
    #pragma unroll
    for (int i=0;i<16;i++){ acc_r[i]=0.f; acc_z[i]=0.f; acc_gn[i]=0.f; acc_ghn[i]=0.f; }

    // chunk 0: k = 0..43  ([xg|xn] rows 0..23, h cols 0..19)
    for (int i=tid; i<KC*192; i+=256){
        int kk = i/192, c = i - kk*192;
        W_s[kk][c] = (kk<24) ? Wx[kk*192+c] : Wh[(kk-24)*192+c];
    }
    for (int i=tid; i<KC*64; i+=256){
        int kk = i>>6, r = i&63;
        long row = row0 + r;
        float v;
        if (kk<12)      v = xg[row*FD+kk];
        else if (kk<24) v = xn[row*FD+(kk-12)];
        else            v = h[row*HDIM + (kk-24)];
        A_s[kk][r]=v;
    }
    __syncthreads();
    #pragma unroll 4
    for (int kk=0;kk<24;kk++){
        v4 av=*(const v4*)&A_s[kk][ty*4];
        v4 wr=*(const v4*)&W_s[kk][tx*4];
        v4 wz=*(const v4*)&W_s[kk][64+tx*4];
        v4 wn=*(const v4*)&W_s[kk][128+tx*4];
        #pragma unroll
        for (int dr=0;dr<4;dr++)
            #pragma unroll
            for (int dc=0;dc<4;dc++){
                acc_r[dr*4+dc]+=av[dr]*wr[dc];
                acc_z[dr*4+dc]+=av[dr]*wz[dc];
                acc_gn[dr*4+dc]+=av[dr]*wn[dc];
            }
    }
    #pragma unroll 4
    for (int kk=24;kk<44;kk++){
        v4 av=*(const v4*)&A_s[kk][ty*4];
        v4 wr=*(const v4*)&W_s[kk][tx*4];
        v4 wz=*(const v4*)&W_s[kk][64+tx*4];
        v4 wn=*(const v4*)&W_s[kk][128+tx*4];
        #pragma unroll
        for (int dr=0;dr<4;dr++)
            #pragma unroll
            for (int dc=0;dc<4;dc++){
                acc_r[dr*4+dc]+=av[dr]*wr[dc];
                acc_z[dr*4+dc]+=av[dr]*wz[dc];
                acc_ghn[dr*4+dc]+=av[dr]*wn[dc];
            }
    }
    __syncthreads();
    // chunk 1: k = 44..87 (Wh rows 20..63, h cols 20..63)
    for (int i=tid; i<KC*192; i+=256){
        int kk = i/192, c = i - kk*192;
        W_s[kk][c] = Wh[(20+kk)*192+c];
    }
    for (int i=tid; i<KC*64; i+=256){
        int kk = i>>6, r = i&63;
        A_s[kk][r] = h[(row0+r)*HDIM + 20 + kk];
    }
    __syncthreads();
    #pragma unroll 4
    for (int kk=0;kk<44;kk++){
        v4 av=*(const v4*)&A_s[kk][ty*4];
        v4 wr=*(const v4*)&W_s[kk][tx*4];
        v4 wz=*(const v4*)&W_s[kk][64+tx*4];
        v4 wn=*(const v4*)&W_s[kk][128+tx*4];
        #pragma unroll
        for (int dr=0;dr<4;dr++)
            #pragma unroll
            for (int dc=0;dc<4;dc++){
                acc_r[dr*4+dc]+=av[dr]*wr[dc];
                acc_z[dr*4+dc]+=av[dr]*wz[dc];
                acc_ghn[dr*4+dc]+=av[dr]*wn[dc];
            }
    }

    // epilogue
    v4 bxr=*(const v4*)&bx[tx*4],     bhr=*(const v4*)&bh[tx*4];
    v4 bxz=*(const v4*)&bx[64+tx*4],  bhz=*(const v4*)&bh[64+tx*4];
    v4 bxn=*(const v4*)&bx[128+tx*4], bhn=*(const v4*)&bh[128+tx*4];
    #pragma unroll
    for (int dr=0;dr<4;dr++){
        long row = row0 + ty*4 + dr;
        v4 hold = *(const v4*)&h[row*HDIM + tx*4];
        v4 hnew;
        #pragma unroll
        for (int dc=0;dc<4;dc++){
            float rr = sigm(acc_r[dr*4+dc] + bxr[dc] + bhr[dc]);
            float zz = sigm(acc_z[dr*4+dc] + bxz[dc] + bhz[dc]);
            float nn = tanh_f(acc_gn[dr*4+dc] + bxn[dc] + rr*(acc_ghn[dr*4+dc] + bhn[dc]));
            hnew[dc] = (1.0f-zz)*nn + zz*hold[dc];
        }
        *(v4*)&h[row*HDIM + tx*4] = hnew;
    }
}

// ---------------- fc ----------------
__global__ void fc_k(const float* __restrict__ h, const float* __restrict__ fc_w,
                     const float* __restrict__ fc_b, float* __restrict__ x_cur,
                     float* __restrict__ out, int p)
{
    int row = blockIdx.x*256+threadIdx.x;
    if (row>=NROWS) return;
    float acc = fc_b[0];
    #pragma unroll
    for (int k=0;k<3;k++){
        const float* hb = h + (long)k*NROWS*HDIM + (long)row*HDIM;
        const float* wb = fc_w + k*HDIM;
        #pragma unroll
        for (int q=0;q<16;q++){
            v4 hv=*(const v4*)&hb[q*4];
            v4 wv=*(const v4*)&wb[q*4];
            acc += hv[0]*wv[0]+hv[1]*wv[1]+hv[2]*wv[2]+hv[3]*wv[3];
        }
    }
    x_cur[row]=acc;
    int b=row/NNODE, n=row-b*NNODE;
    out[((long)b*PRED + p)*NNODE + n] = acc;
}

extern "C" void kernel_launch(void* const* d_in, const int* in_sizes, int n_in,
                              void* d_out, int out_size, void* d_ws, size_t ws_size,
                              hipStream_t stream)
{
    const float* x_hist   = (const float*)d_in[0];
    const float* enc_misc = (const float*)d_in[1];
    const float* dec      = (const float*)d_in[2];
    const float* We       = (const float*)d_in[3];
    const float* be       = (const float*)d_in[4];
    const float* Wx       = (const float*)d_in[5];
    const float* Wh       = (const float*)d_in[6];
    const float* bx       = (const float*)d_in[7];
    const float* bh       = (const float*)d_in[8];
    const float* fc_w     = (const float*)d_in[9];
    const float* fc_b     = (const float*)d_in[10];
    const int*   src      = (const int*)d_in[11];
    const int*   dst      = (const int*)d_in[12];
    float* out = (float*)d_out;

    // workspace layout (~67 MB)
    float* h    = (float*)d_ws;                         // 3 * NROWS * HDIM
    float* xn   = h  + (size_t)3*NROWS*HDIM;            // NROWS*12
    float* xg1  = xn + (size_t)NROWS*FD;
    float* xg2  = xg1 + (size_t)NROWS*FD;
    float* xg3  = xg2 + (size_t)NROWS*FD;
    float* x_cur= xg3 + (size_t)NROWS*FD;               // NROWS
    int*   deg  = (int*)(x_cur + NROWS);                // NNODE
    int*   offs = deg + NNODE;                          // NNODE+1
    int*   curs = offs + NNODE + 1;                     // NNODE
    int*   elist= curs + NNODE;                         // NE

    hipMemsetAsync(h, 0, (size_t)3*NROWS*HDIM*sizeof(float), stream);
    hipMemsetAsync(deg, 0, NNODE*sizeof(int), stream);

    const int gE = (NE+255)/256;           // 68
    csr_count_k<<<gE,256,0,stream>>>(dst, deg);
    csr_scan_k<<<1,1024,0,stream>>>(deg, offs, curs);
    csr_fill_k<<<gE,256,0,stream>>>(dst, curs, elist);

    const int gRow  = (NROWS+255)/256;     // 272
    const int gGat  = NB*8;                // 512
    const int gGru  = NROWS/64;            // 1085

    auto step = [&](const float* xsrc, long xs_bs, long xs_off,
                    const float* feat, long f_bs, long f_off){
        build_xn_k<<<gRow,256,0,stream>>>(xsrc,xs_bs,xs_off,feat,f_bs,f_off,xn);
        gnn_gather_k<<<gGat,256,0,stream>>>(xn, We,be,src,dst,elist,offs, xg1);
        gru_k<<<gGru,256,0,stream>>>(xg1,xn,h,                     Wx,          Wh,          bx,      bh);
        gnn_gather_k<<<gGat,256,0,stream>>>(xg1,We,be,src,dst,elist,offs, xg2);
        gru_k<<<gGru,256,0,stream>>>(xg2,xn,h+(size_t)NROWS*HDIM,  Wx+24*192,   Wh+64*192,   bx+192,  bh+192);
        gnn_gather_k<<<gGat,256,0,stream>>>(xg2,We,be,src,dst,elist,offs, xg3);
        gru_k<<<gGru,256,0,stream>>>(xg3,xn,h+(size_t)2*NROWS*HDIM,Wx+2*24*192, Wh+2*64*192, bx+2*192,bh+2*192);
    };

    // history: t = 0..22, features slice t+1 (from enc_misc)
    for (int t=0;t<HIST-1;t++)
        step(x_hist,(long)HIST*NNODE,(long)t*NNODE,
             enc_misc,(long)HIST*NNODE*FMD,(long)(t+1)*NNODE*FMD);

    // prediction: p = 0..23, features = dec[:,p]; x feedback via x_cur
    for (int p=0;p<PRED;p++){
        if (p==0)
            step(x_hist,(long)HIST*NNODE,(long)(HIST-1)*NNODE,
                 dec,(long)PRED*NNODE*FMD,(long)p*NNODE*FMD);
        else
            step(x_cur,(long)NNODE,0L,
                 dec,(long)PRED*NNODE*FMD,(long)p*NNODE*FMD);
        fc_k<<<gRow,256,0,stream>>>(h, fc_w, fc_b, x_cur, out, p);
    }
}

// Round 3
// 14421.184 us; speedup vs baseline: 7.4890x; 1.5789x over previous
//
#include <hip/hip_runtime.h>

#define NB 64
#define NNODE 1085
#define HIST 24
#define PRED 24
#define KHOP 3
#define HDIM 64
#define FXD 1
#define FMD 11
#define FD 12
#define NE 17360
#define NROWS (NB*NNODE)   // 69440
#define CHUNK 136          // nodes per gather chunk (8 chunks cover 1085)

typedef float v4 __attribute__((ext_vector_type(4)));

__device__ __forceinline__ float sigm(float x){ return 1.0f/(1.0f + __expf(-x)); }
__device__ __forceinline__ float tanh_f(float x){ return 1.0f - 2.0f/(__expf(2.0f*x)+1.0f); }

// ---------------- CSR build (once per launch) ----------------
__global__ void csr_count_k(const int* __restrict__ dst, int* __restrict__ deg)
{
    int e = blockIdx.x*256 + threadIdx.x;
    if (e < NE) atomicAdd(&deg[dst[e]], 1);
}

__global__ __launch_bounds__(1024) void csr_scan_k(const int* __restrict__ deg,
                                                   int* __restrict__ offs, int* __restrict__ curs)
{
    __shared__ int s[2][2048];
    int t = threadIdx.x;
    for (int i=t;i<2048;i+=1024) s[0][i] = (i<NNODE) ? deg[i] : 0;
    __syncthreads();
    int cur = 0;
    for (int d=1; d<2048; d<<=1){
        for (int i=t;i<2048;i+=1024){
            int v = s[cur][i];
            if (i>=d) v += s[cur][i-d];
            s[cur^1][i] = v;
        }
        __syncthreads();
        cur ^= 1;
    }
    for (int i=t;i<=NNODE;i+=1024){
        int v = (i==0) ? 0 : s[cur][i-1];
        offs[i] = v;
        if (i<NNODE) curs[i] = v;
    }
}

__global__ void csr_fill_k(const int* __restrict__ dst, int* __restrict__ curs,
                           int* __restrict__ elist)
{
    int e = blockIdx.x*256 + threadIdx.x;
    if (e < NE){
        int d = dst[e];
        int p = atomicAdd(&curs[d], 1);
        elist[p] = e;
    }
}

// ---------------- build xn = concat([x_scalar, feat11]) ----------------
__global__ void build_xn_k(const float* __restrict__ xsrc, long xs_bs, long xs_off,
                           const float* __restrict__ feat, long f_bs, long f_off,
                           float* __restrict__ xn)
{
    int row = blockIdx.x*256 + threadIdx.x;
    if (row >= NROWS) return;
    int b = row / NNODE, n = row - b*NNODE;
    float v[12];
    v[0] = xsrc[(long)b*xs_bs + xs_off + n];
    const float* fp = feat + (long)b*f_bs + f_off + (long)n*FMD;
    #pragma unroll
    for (int i=0;i<FMD;i++) v[1+i] = fp[i];
    v4* xp = (v4*)(xn + (long)row*FD);
    #pragma unroll
    for (int q=0;q<3;q++){
        v4 tq; tq[0]=v[4*q]; tq[1]=v[4*q+1]; tq[2]=v[4*q+2]; tq[3]=v[4*q+3];
        xp[q]=tq;
    }
}

// ---------------- GNN hop: CSR gather, contiguous-run register accumulation ----------------
// block = (batch, node-chunk). Stages x[b] in LDS. Each thread takes a CONTIGUOUS
// run of dst-sorted edges, accumulates relu(MLP) in registers, flushes to LDS only
// on dst change (~1.5 flushes/thread). dst-half of the MLP hoisted per run.
__global__ __launch_bounds__(256) void gnn_gather_k(const float* __restrict__ x,
    const float* __restrict__ We, const float* __restrict__ be,
    const int* __restrict__ src, const int* __restrict__ dst,
    const int* __restrict__ elist, const int* __restrict__ offs,
    float* __restrict__ out)
{
    __shared__ __align__(16) float x_s[NNODE*FD];    // 52080 B
    __shared__ __align__(16) float acc_s[CHUNK*FD];  // 6528 B
    __shared__ __align__(16) float w_s[288];
    __shared__ float be_s[12];
    const int t = threadIdx.x;
    const int b = blockIdx.x >> 3, c = blockIdx.x & 7;
    const int n0 = c*CHUNK, n1 = min(NNODE, n0+CHUNK);

    const v4* xg4 = (const v4*)(x + (long)b*NNODE*FD);
    for (int i=t; i<NNODE*FD/4; i+=256) ((v4*)x_s)[i] = xg4[i];
    for (int i=t; i<288; i+=256) w_s[i]=We[i];
    if (t<12) be_s[t]=be[t];
    for (int i=t; i<(n1-n0)*FD; i+=256) acc_s[i]=0.f;
    __syncthreads();

    const int e_beg = offs[n0], e_end = offs[n1];
    const int total = e_end - e_beg;
    const int L = (total + 255) >> 8;
    const int my_beg = e_beg + t*L;
    const int my_end = min(my_beg + L, e_end);

    float accr[12];   // running sum of relu(m) for current dst run
    float part[12];   // be + W[12:24]·x_dst for current run
    int cur = -1;

    for (int idx=my_beg; idx<my_end; ++idx){
        int e = elist[idx];
        int sN = src[e], dN = dst[e];
        if (dN != cur){
            if (cur >= 0){
                float* ab = &acc_s[(cur-n0)*FD];
                #pragma unroll
                for (int f=0;f<12;f++) atomicAdd(&ab[f], accr[f]);
            }
            cur = dN;
            #pragma unroll
            for (int f=0;f<12;f++){ accr[f]=0.f; part[f]=be_s[f]; }
            const v4* xdv = (const v4*)&x_s[dN*FD];
            #pragma unroll
            for (int q=0;q<3;q++){
                v4 cc = xdv[q];
                #pragma unroll
                for (int j=0;j<4;j++){
                    float xv = cc[j];
                    int i = (12 + 4*q + j)*12;
                    v4 w0=*(const v4*)&w_s[i];
                    v4 w1=*(const v4*)&w_s[i+4];
                    v4 w2=*(const v4*)&w_s[i+8];
                    #pragma unroll
                    for (int jj=0;jj<4;jj++){
                        part[jj]   += xv*w0[jj];
                        part[4+jj] += xv*w1[jj];
                        part[8+jj] += xv*w2[jj];
                    }
                }
            }
        }
        float m[12];
        #pragma unroll
        for (int f=0;f<12;f++) m[f]=part[f];
        const v4* xsv = (const v4*)&x_s[sN*FD];
        #pragma unroll
        for (int q=0;q<3;q++){
            v4 a = xsv[q];
            #pragma unroll
            for (int j=0;j<4;j++){
                float xv = a[j];
                int i = (4*q + j)*12;
                v4 w0=*(const v4*)&w_s[i];
                v4 w1=*(const v4*)&w_s[i+4];
                v4 w2=*(const v4*)&w_s[i+8];
                #pragma unroll
                for (int jj=0;jj<4;jj++){
                    m[jj]   += xv*w0[jj];
                    m[4+jj] += xv*w1[jj];
                    m[8+jj] += xv*w2[jj];
                }
            }
        }
        #pragma unroll
        for (int f=0;f<12;f++) accr[f] += fmaxf(m[f], 0.f);
    }
    if (cur >= 0){
        float* ab = &acc_s[(cur-n0)*FD];
        #pragma unroll
        for (int f=0;f<12;f++) atomicAdd(&ab[f], accr[f]);
    }
    __syncthreads();

    const int cnt4 = (n1-n0)*FD/4;
    const v4* xs4 = (const v4*)&x_s[n0*FD];
    const v4* ac4 = (const v4*)acc_s;
    v4* ob4 = (v4*)(out + ((long)b*NNODE + n0)*FD);
    for (int i=t; i<cnt4; i+=256) ob4[i] = xs4[i] + ac4[i];
}

// ---------------- Fused GRU ----------------
#define KC 44
__global__ __launch_bounds__(256) void gru_k(const float* __restrict__ xg, const float* __restrict__ xn,
    float* __restrict__ h, const float* __restrict__ Wx, const float* __restrict__ Wh,
    const float* __restrict__ bx, const float* __restrict__ bh)
{
    __shared__ __align__(16) float A_s[KC][64];
    __shared__ __align__(16) float W_s[KC][192];
    const int tid = threadIdx.x;
    const int tx = tid & 15, ty = tid >> 4;
    const long row0 = (long)blockIdx.x * 64;

    float acc_r[16], acc_z[16], acc_gn[16], acc_ghn[16];
    #pragma unroll
    for (int i=0;i<16;i++){ acc_r[i]=0.f; acc_z[i]=0.f; acc_gn[i]=0.f; acc_ghn[i]=0.f; }

    // chunk 0: k = 0..43  ([xg|xn] rows 0..23, h cols 0..19)
    for (int i=tid; i<KC*192; i+=256){
        int kk = i/192, c = i - kk*192;
        W_s[kk][c] = (kk<24) ? Wx[kk*192+c] : Wh[(kk-24)*192+c];
    }
    for (int i=tid; i<KC*64; i+=256){
        int kk = i>>6, r = i&63;
        long row = row0 + r;
        float v;
        if (kk<12)      v = xg[row*FD+kk];
        else if (kk<24) v = xn[row*FD+(kk-12)];
        else            v = h[row*HDIM + (kk-24)];
        A_s[kk][r]=v;
    }
    __syncthreads();
    #pragma unroll 4
    for (int kk=0;kk<24;kk++){
        v4 av=*(const v4*)&A_s[kk][ty*4];
        v4 wr=*(const v4*)&W_s[kk][tx*4];
        v4 wz=*(const v4*)&W_s[kk][64+tx*4];
        v4 wn=*(const v4*)&W_s[kk][128+tx*4];
        #pragma unroll
        for (int dr=0;dr<4;dr++)
            #pragma unroll
            for (int dc=0;dc<4;dc++){
                acc_r[dr*4+dc]+=av[dr]*wr[dc];
                acc_z[dr*4+dc]+=av[dr]*wz[dc];
                acc_gn[dr*4+dc]+=av[dr]*wn[dc];
            }
    }
    #pragma unroll 4
    for (int kk=24;kk<44;kk++){
        v4 av=*(const v4*)&A_s[kk][ty*4];
        v4 wr=*(const v4*)&W_s[kk][tx*4];
        v4 wz=*(const v4*)&W_s[kk][64+tx*4];
        v4 wn=*(const v4*)&W_s[kk][128+tx*4];
        #pragma unroll
        for (int dr=0;dr<4;dr++)
            #pragma unroll
            for (int dc=0;dc<4;dc++){
                acc_r[dr*4+dc]+=av[dr]*wr[dc];
                acc_z[dr*4+dc]+=av[dr]*wz[dc];
                acc_ghn[dr*4+dc]+=av[dr]*wn[dc];
            }
    }
    __syncthreads();
    // chunk 1: k = 44..87 (Wh rows 20..63, h cols 20..63)
    for (int i=tid; i<KC*192; i+=256){
        int kk = i/192, c = i - kk*192;
        W_s[kk][c] = Wh[(20+kk)*192+c];
    }
    for (int i=tid; i<KC*64; i+=256){
        int kk = i>>6, r = i&63;
        A_s[kk][r] = h[(row0+r)*HDIM + 20 + kk];
    }
    __syncthreads();
    #pragma unroll 4
    for (int kk=0;kk<44;kk++){
        v4 av=*(const v4*)&A_s[kk][ty*4];
        v4 wr=*(const v4*)&W_s[kk][tx*4];
        v4 wz=*(const v4*)&W_s[kk][64+tx*4];
        v4 wn=*(const v4*)&W_s[kk][128+tx*4];
        #pragma unroll
        for (int dr=0;dr<4;dr++)
            #pragma unroll
            for (int dc=0;dc<4;dc++){
                acc_r[dr*4+dc]+=av[dr]*wr[dc];
                acc_z[dr*4+dc]+=av[dr]*wz[dc];
                acc_ghn[dr*4+dc]+=av[dr]*wn[dc];
            }
    }

    // epilogue
    v4 bxr=*(const v4*)&bx[tx*4],     bhr=*(const v4*)&bh[tx*4];
    v4 bxz=*(const v4*)&bx[64+tx*4],  bhz=*(const v4*)&bh[64+tx*4];
    v4 bxn=*(const v4*)&bx[128+tx*4], bhn=*(const v4*)&bh[128+tx*4];
    #pragma unroll
    for (int dr=0;dr<4;dr++){
        long row = row0 + ty*4 + dr;
        v4 hold = *(const v4*)&h[row*HDIM + tx*4];
        v4 hnew;
        #pragma unroll
        for (int dc=0;dc<4;dc++){
            float rr = sigm(acc_r[dr*4+dc] + bxr[dc] + bhr[dc]);
            float zz = sigm(acc_z[dr*4+dc] + bxz[dc] + bhz[dc]);
            float nn = tanh_f(acc_gn[dr*4+dc] + bxn[dc] + rr*(acc_ghn[dr*4+dc] + bhn[dc]));
            hnew[dc] = (1.0f-zz)*nn + zz*hold[dc];
        }
        *(v4*)&h[row*HDIM + tx*4] = hnew;
    }
}

// ---------------- fc ----------------
__global__ void fc_k(const float* __restrict__ h, const float* __restrict__ fc_w,
                     const float* __restrict__ fc_b, float* __restrict__ x_cur,
                     float* __restrict__ out, int p)
{
    int row = blockIdx.x*256+threadIdx.x;
    if (row>=NROWS) return;
    float acc = fc_b[0];
    #pragma unroll
    for (int k=0;k<3;k++){
        const float* hb = h + (long)k*NROWS*HDIM + (long)row*HDIM;
        const float* wb = fc_w + k*HDIM;
        #pragma unroll
        for (int q=0;q<16;q++){
            v4 hv=*(const v4*)&hb[q*4];
            v4 wv=*(const v4*)&wb[q*4];
            acc += hv[0]*wv[0]+hv[1]*wv[1]+hv[2]*wv[2]+hv[3]*wv[3];
        }
    }
    x_cur[row]=acc;
    int b=row/NNODE, n=row-b*NNODE;
    out[((long)b*PRED + p)*NNODE + n] = acc;
}

extern "C" void kernel_launch(void* const* d_in, const int* in_sizes, int n_in,
                              void* d_out, int out_size, void* d_ws, size_t ws_size,
                              hipStream_t stream)
{
    const float* x_hist   = (const float*)d_in[0];
    const float* enc_misc = (const float*)d_in[1];
    const float* dec      = (const float*)d_in[2];
    const float* We       = (const float*)d_in[3];
    const float* be       = (const float*)d_in[4];
    const float* Wx       = (const float*)d_in[5];
    const float* Wh       = (const float*)d_in[6];
    const float* bx       = (const float*)d_in[7];
    const float* bh       = (const float*)d_in[8];
    const float* fc_w     = (const float*)d_in[9];
    const float* fc_b     = (const float*)d_in[10];
    const int*   src      = (const int*)d_in[11];
    const int*   dst      = (const int*)d_in[12];
    float* out = (float*)d_out;

    // workspace layout (~67 MB)
    float* h    = (float*)d_ws;                         // 3 * NROWS * HDIM
    float* xn   = h  + (size_t)3*NROWS*HDIM;            // NROWS*12
    float* xg1  = xn + (size_t)NROWS*FD;
    float* xg2  = xg1 + (size_t)NROWS*FD;
    float* xg3  = xg2 + (size_t)NROWS*FD;
    float* x_cur= xg3 + (size_t)NROWS*FD;               // NROWS
    int*   deg  = (int*)(x_cur + NROWS);                // NNODE
    int*   offs = deg + NNODE;                          // NNODE+1
    int*   curs = offs + NNODE + 1;                     // NNODE
    int*   elist= curs + NNODE;                         // NE

    hipMemsetAsync(h, 0, (size_t)3*NROWS*HDIM*sizeof(float), stream);
    hipMemsetAsync(deg, 0, NNODE*sizeof(int), stream);

    const int gE = (NE+255)/256;           // 68
    csr_count_k<<<gE,256,0,stream>>>(dst, deg);
    csr_scan_k<<<1,1024,0,stream>>>(deg, offs, curs);
    csr_fill_k<<<gE,256,0,stream>>>(dst, curs, elist);

    const int gRow  = (NROWS+255)/256;     // 272
    const int gGat  = NB*8;                // 512
    const int gGru  = NROWS/64;            // 1085

    auto step = [&](const float* xsrc, long xs_bs, long xs_off,
                    const float* feat, long f_bs, long f_off){
        build_xn_k<<<gRow,256,0,stream>>>(xsrc,xs_bs,xs_off,feat,f_bs,f_off,xn);
        gnn_gather_k<<<gGat,256,0,stream>>>(xn, We,be,src,dst,elist,offs, xg1);
        gru_k<<<gGru,256,0,stream>>>(xg1,xn,h,                     Wx,          Wh,          bx,      bh);
        gnn_gather_k<<<gGat,256,0,stream>>>(xg1,We,be,src,dst,elist,offs, xg2);
        gru_k<<<gGru,256,0,stream>>>(xg2,xn,h+(size_t)NROWS*HDIM,  Wx+24*192,   Wh+64*192,   bx+192,  bh+192);
        gnn_gather_k<<<gGat,256,0,stream>>>(xg2,We,be,src,dst,elist,offs, xg3);
        gru_k<<<gGru,256,0,stream>>>(xg3,xn,h+(size_t)2*NROWS*HDIM,Wx+2*24*192, Wh+2*64*192, bx+2*192,bh+2*192);
    };

    // history: t = 0..22, features slice t+1 (from enc_misc)
    for (int t=0;t<HIST-1;t++)
        step(x_hist,(long)HIST*NNODE,(long)t*NNODE,
             enc_misc,(long)HIST*NNODE*FMD,(long)(t+1)*NNODE*FMD);

    // prediction: p = 0..23, features = dec[:,p]; x feedback via x_cur
    for (int p=0;p<PRED;p++){
        if (p==0)
            step(x_hist,(long)HIST*NNODE,(long)(HIST-1)*NNODE,
                 dec,(long)PRED*NNODE*FMD,(long)p*NNODE*FMD);
        else
            step(x_cur,(long)NNODE,0L,
                 dec,(long)PRED*NNODE*FMD,(long)p*NNODE*FMD);
        fc_k<<<gRow,256,0,stream>>>(h, fc_w, fc_b, x_cur, out, p);
    }
}

// Round 4
// 12019.555 us; speedup vs baseline: 8.9854x; 1.1998x over previous
//
#include <hip/hip_runtime.h>

#define NB 64
#define NNODE 1085
#define HIST 24
#define PRED 24
#define KHOP 3
#define HDIM 64
#define FXD 1
#define FMD 11
#define FD 12
#define NE 17360
#define NROWS (NB*NNODE)   // 69440
#define CHUNK 136          // nodes per gather chunk (8 chunks cover 1085)

typedef float v4 __attribute__((ext_vector_type(4)));

__device__ __forceinline__ float sigm(float x){ return 1.0f/(1.0f + __expf(-x)); }
__device__ __forceinline__ float tanh_f(float x){ return 1.0f - 2.0f/(__expf(2.0f*x)+1.0f); }

// ---------------- CSR build (once per launch) ----------------
__global__ void csr_count_k(const int* __restrict__ dst, int* __restrict__ deg)
{
    int e = blockIdx.x*256 + threadIdx.x;
    if (e < NE) atomicAdd(&deg[dst[e]], 1);
}

__global__ __launch_bounds__(1024) void csr_scan_k(const int* __restrict__ deg,
                                                   int* __restrict__ offs, int* __restrict__ curs)
{
    __shared__ int s[2][2048];
    int t = threadIdx.x;
    for (int i=t;i<2048;i+=1024) s[0][i] = (i<NNODE) ? deg[i] : 0;
    __syncthreads();
    int cur = 0;
    for (int d=1; d<2048; d<<=1){
        for (int i=t;i<2048;i+=1024){
            int v = s[cur][i];
            if (i>=d) v += s[cur][i-d];
            s[cur^1][i] = v;
        }
        __syncthreads();
        cur ^= 1;
    }
    for (int i=t;i<=NNODE;i+=1024){
        int v = (i==0) ? 0 : s[cur][i-1];
        offs[i] = v;
        if (i<NNODE) curs[i] = v;
    }
}

__global__ void csr_fill_k(const int* __restrict__ dst, int* __restrict__ curs,
                           int* __restrict__ elist)
{
    int e = blockIdx.x*256 + threadIdx.x;
    if (e < NE){
        int d = dst[e];
        int p = atomicAdd(&curs[d], 1);
        elist[p] = e;
    }
}

// ---------------- hist-phase batched feature build ----------------
// xn_all[ti][row][12] = concat(x_hist[b, t0+ti, n], enc_misc[b, t0+ti+1, n, :])
__global__ void build_hist_k(const float* __restrict__ x_hist, const float* __restrict__ enc_misc,
                             int t0, int T, float* __restrict__ xn_all)
{
    int idx = blockIdx.x*256 + threadIdx.x;
    if (idx >= T*NROWS) return;
    int ti = idx / NROWS, row = idx - ti*NROWS;
    int b = row / NNODE, n = row - b*NNODE;
    int t = t0 + ti;
    float v[12];
    v[0] = x_hist[((long)b*HIST + t)*NNODE + n];
    const float* fp = enc_misc + (((long)b*HIST + (t+1))*NNODE + n)*FMD;
    #pragma unroll
    for (int i=0;i<FMD;i++) v[1+i] = fp[i];
    v4* xp = (v4*)(xn_all + ((long)ti*NROWS + row)*FD);
    #pragma unroll
    for (int q=0;q<3;q++){
        v4 tq; tq[0]=v[4*q]; tq[1]=v[4*q+1]; tq[2]=v[4*q+2]; tq[3]=v[4*q+3];
        xp[q]=tq;
    }
}

// ---------------- single-step feature build (pred phase) ----------------
__global__ void build_xn_k(const float* __restrict__ xsrc, long xs_bs, long xs_off,
                           const float* __restrict__ feat, long f_bs, long f_off,
                           float* __restrict__ xn)
{
    int row = blockIdx.x*256 + threadIdx.x;
    if (row >= NROWS) return;
    int b = row / NNODE, n = row - b*NNODE;
    float v[12];
    v[0] = xsrc[(long)b*xs_bs + xs_off + n];
    const float* fp = feat + (long)b*f_bs + f_off + (long)n*FMD;
    #pragma unroll
    for (int i=0;i<FMD;i++) v[1+i] = fp[i];
    v4* xp = (v4*)(xn + (long)row*FD);
    #pragma unroll
    for (int q=0;q<3;q++){
        v4 tq; tq[0]=v[4*q]; tq[1]=v[4*q+1]; tq[2]=v[4*q+2]; tq[3]=v[4*q+3];
        xp[q]=tq;
    }
}

// ---------------- GNN hop: CSR gather, batched over ti (blockIdx.y) ----------------
__global__ __launch_bounds__(256) void gnn_gather_k(const float* __restrict__ xin,
    const float* __restrict__ We, const float* __restrict__ be,
    const int* __restrict__ src, const int* __restrict__ dst,
    const int* __restrict__ elist, const int* __restrict__ offs,
    float* __restrict__ xout)
{
    __shared__ __align__(16) float x_s[NNODE*FD];    // 52080 B
    __shared__ __align__(16) float acc_s[CHUNK*FD];  // 6528 B
    __shared__ __align__(16) float w_s[288];
    __shared__ float be_s[12];
    const int t = threadIdx.x;
    const int b = blockIdx.x >> 3, c = blockIdx.x & 7;
    const long ti = blockIdx.y;
    const int n0 = c*CHUNK, n1 = min(NNODE, n0+CHUNK);
    const float* x = xin + ti*NROWS*FD;

    const v4* xg4 = (const v4*)(x + (long)b*NNODE*FD);
    for (int i=t; i<NNODE*FD/4; i+=256) ((v4*)x_s)[i] = xg4[i];
    for (int i=t; i<288; i+=256) w_s[i]=We[i];
    if (t<12) be_s[t]=be[t];
    for (int i=t; i<(n1-n0)*FD; i+=256) acc_s[i]=0.f;
    __syncthreads();

    const int e_beg = offs[n0], e_end = offs[n1];
    const int total = e_end - e_beg;
    const int L = (total + 255) >> 8;
    const int my_beg = e_beg + t*L;
    const int my_end = min(my_beg + L, e_end);

    float accr[12];
    float part[12];
    int cur = -1;

    for (int idx=my_beg; idx<my_end; ++idx){
        int e = elist[idx];
        int sN = src[e], dN = dst[e];
        if (dN != cur){
            if (cur >= 0){
                float* ab = &acc_s[(cur-n0)*FD];
                #pragma unroll
                for (int f=0;f<12;f++) atomicAdd(&ab[f], accr[f]);
            }
            cur = dN;
            #pragma unroll
            for (int f=0;f<12;f++){ accr[f]=0.f; part[f]=be_s[f]; }
            const v4* xdv = (const v4*)&x_s[dN*FD];
            #pragma unroll
            for (int q=0;q<3;q++){
                v4 cc = xdv[q];
                #pragma unroll
                for (int j=0;j<4;j++){
                    float xv = cc[j];
                    int i = (12 + 4*q + j)*12;
                    v4 w0=*(const v4*)&w_s[i];
                    v4 w1=*(const v4*)&w_s[i+4];
                    v4 w2=*(const v4*)&w_s[i+8];
                    #pragma unroll
                    for (int jj=0;jj<4;jj++){
                        part[jj]   += xv*w0[jj];
                        part[4+jj] += xv*w1[jj];
                        part[8+jj] += xv*w2[jj];
                    }
                }
            }
        }
        float m[12];
        #pragma unroll
        for (int f=0;f<12;f++) m[f]=part[f];
        const v4* xsv = (const v4*)&x_s[sN*FD];
        #pragma unroll
        for (int q=0;q<3;q++){
            v4 a = xsv[q];
            #pragma unroll
            for (int j=0;j<4;j++){
                float xv = a[j];
                int i = (4*q + j)*12;
                v4 w0=*(const v4*)&w_s[i];
                v4 w1=*(const v4*)&w_s[i+4];
                v4 w2=*(const v4*)&w_s[i+8];
                #pragma unroll
                for (int jj=0;jj<4;jj++){
                    m[jj]   += xv*w0[jj];
                    m[4+jj] += xv*w1[jj];
                    m[8+jj] += xv*w2[jj];
                }
            }
        }
        #pragma unroll
        for (int f=0;f<12;f++) accr[f] += fmaxf(m[f], 0.f);
    }
    if (cur >= 0){
        float* ab = &acc_s[(cur-n0)*FD];
        #pragma unroll
        for (int f=0;f<12;f++) atomicAdd(&ab[f], accr[f]);
    }
    __syncthreads();

    const int cnt4 = (n1-n0)*FD/4;
    const v4* xs4 = (const v4*)&x_s[n0*FD];
    const v4* ac4 = (const v4*)acc_s;
    v4* ob4 = (v4*)(xout + ti*NROWS*FD + ((long)b*NNODE + n0)*FD);
    for (int i=t; i<cnt4; i+=256) ob4[i] = xs4[i] + ac4[i];
}

// ---------------- Fused GRU, batched over the 3 hops (blockIdx.y = k) ----------------
// A-matrix staged via coalesced v4 loads + transposed LDS writes.
#define KC 44
__global__ __launch_bounds__(256) void gru3_k(
    const float* __restrict__ xg_base, long k_stride,      // xg for hop k = xg_base + k*k_stride
    const float* __restrict__ xn,
    float* __restrict__ h_base,
    const float* __restrict__ Wx, const float* __restrict__ Wh,
    const float* __restrict__ bx, const float* __restrict__ bh)
{
    const int k = blockIdx.y;
    const float* xg  = xg_base + (long)k*k_stride;
    float*       h   = h_base + (size_t)k*NROWS*HDIM;
    const float* wx  = Wx + (size_t)k*24*192;
    const float* wh  = Wh + (size_t)k*64*192;
    const float* bxk = bx + k*192;
    const float* bhk = bh + k*192;

    __shared__ __align__(16) float A_s[KC][64];
    __shared__ __align__(16) float W_s[KC][192];
    const int tid = threadIdx.x;
    const int tx = tid & 15, ty = tid >> 4;
    const long row0 = (long)blockIdx.x * 64;

    const v4* xg4 = (const v4*)(xg + row0*FD);
    const v4* xn4 = (const v4*)(xn + row0*FD);
    const v4* h4  = (const v4*)(h  + row0*HDIM);
    const v4* wx4 = (const v4*)wx;
    const v4* wh4 = (const v4*)wh;

    float acc_r[16], acc_z[16], acc_gn[16], acc_ghn[16];
    #pragma unroll
    for (int i=0;i<16;i++){ acc_r[i]=0.f; acc_z[i]=0.f; acc_gn[i]=0.f; acc_ghn[i]=0.f; }

    // ---- chunk 0: A rows 0..23 = [xg|xn], 24..43 = h cols 0..19 ----
    for (int i=tid; i<KC*48; i+=256){
        int kk = i/48, q = i - kk*48;
        v4 w = (kk<24) ? wx4[kk*48+q] : wh4[(kk-24)*48+q];
        *(v4*)&W_s[kk][q*4] = w;
    }
    for (int i=tid; i<192; i+=256){                 // xg: 64 rows x 3 v4
        int r = i/3, q = i - r*3;
        v4 v = xg4[r*3+q];
        #pragma unroll
        for (int j=0;j<4;j++) A_s[4*q+j][r] = v[j];
    }
    for (int i=tid; i<192; i+=256){                 // xn
        int r = i/3, q = i - r*3;
        v4 v = xn4[r*3+q];
        #pragma unroll
        for (int j=0;j<4;j++) A_s[12+4*q+j][r] = v[j];
    }
    for (int i=tid; i<320; i+=256){                 // h cols 0..19: 64 rows x 5 v4
        int r = i/5, q = i - r*5;
        v4 v = h4[r*16+q];
        #pragma unroll
        for (int j=0;j<4;j++) A_s[24+4*q+j][r] = v[j];
    }
    __syncthreads();
    #pragma unroll 4
    for (int kk=0;kk<24;kk++){
        v4 av=*(const v4*)&A_s[kk][ty*4];
        v4 wr=*(const v4*)&W_s[kk][tx*4];
        v4 wz=*(const v4*)&W_s[kk][64+tx*4];
        v4 wn=*(const v4*)&W_s[kk][128+tx*4];
        #pragma unroll
        for (int dr=0;dr<4;dr++)
            #pragma unroll
            for (int dc=0;dc<4;dc++){
                acc_r[dr*4+dc]+=av[dr]*wr[dc];
                acc_z[dr*4+dc]+=av[dr]*wz[dc];
                acc_gn[dr*4+dc]+=av[dr]*wn[dc];
            }
    }
    #pragma unroll 4
    for (int kk=24;kk<44;kk++){
        v4 av=*(const v4*)&A_s[kk][ty*4];
        v4 wr=*(const v4*)&W_s[kk][tx*4];
        v4 wz=*(const v4*)&W_s[kk][64+tx*4];
        v4 wn=*(const v4*)&W_s[kk][128+tx*4];
        #pragma unroll
        for (int dr=0;dr<4;dr++)
            #pragma unroll
            for (int dc=0;dc<4;dc++){
                acc_r[dr*4+dc]+=av[dr]*wr[dc];
                acc_z[dr*4+dc]+=av[dr]*wz[dc];
                acc_ghn[dr*4+dc]+=av[dr]*wn[dc];
            }
    }
    __syncthreads();
    // ---- chunk 1: A rows 0..43 = h cols 20..63 ----
    for (int i=tid; i<KC*48; i+=256){
        int kk = i/48, q = i - kk*48;
        *(v4*)&W_s[kk][q*4] = wh4[(20+kk)*48+q];
    }
    for (int i=tid; i<704; i+=256){                 // h cols 20..63: 64 rows x 11 v4
        int r = i/11, q = i - r*11;
        v4 v = h4[r*16+5+q];
        #pragma unroll
        for (int j=0;j<4;j++) A_s[4*q+j][r] = v[j];
    }
    __syncthreads();
    #pragma unroll 4
    for (int kk=0;kk<44;kk++){
        v4 av=*(const v4*)&A_s[kk][ty*4];
        v4 wr=*(const v4*)&W_s[kk][tx*4];
        v4 wz=*(const v4*)&W_s[kk][64+tx*4];
        v4 wn=*(const v4*)&W_s[kk][128+tx*4];
        #pragma unroll
        for (int dr=0;dr<4;dr++)
            #pragma unroll
            for (int dc=0;dc<4;dc++){
                acc_r[dr*4+dc]+=av[dr]*wr[dc];
                acc_z[dr*4+dc]+=av[dr]*wz[dc];
                acc_ghn[dr*4+dc]+=av[dr]*wn[dc];
            }
    }

    // ---- epilogue ----
    v4 bxr=*(const v4*)&bxk[tx*4],     bhr=*(const v4*)&bhk[tx*4];
    v4 bxz=*(const v4*)&bxk[64+tx*4],  bhz=*(const v4*)&bhk[64+tx*4];
    v4 bxn=*(const v4*)&bxk[128+tx*4], bhn=*(const v4*)&bhk[128+tx*4];
    #pragma unroll
    for (int dr=0;dr<4;dr++){
        long row = row0 + ty*4 + dr;
        v4 hold = *(const v4*)&h[row*HDIM + tx*4];
        v4 hnew;
        #pragma unroll
        for (int dc=0;dc<4;dc++){
            float rr = sigm(acc_r[dr*4+dc] + bxr[dc] + bhr[dc]);
            float zz = sigm(acc_z[dr*4+dc] + bxz[dc] + bhz[dc]);
            float nn = tanh_f(acc_gn[dr*4+dc] + bxn[dc] + rr*(acc_ghn[dr*4+dc] + bhn[dc]));
            hnew[dc] = (1.0f-zz)*nn + zz*hold[dc];
        }
        *(v4*)&h[row*HDIM + tx*4] = hnew;
    }
}

// ---------------- fc ----------------
__global__ void fc_k(const float* __restrict__ h, const float* __restrict__ fc_w,
                     const float* __restrict__ fc_b, float* __restrict__ x_cur,
                     float* __restrict__ out, int p)
{
    int row = blockIdx.x*256+threadIdx.x;
    if (row>=NROWS) return;
    float acc = fc_b[0];
    #pragma unroll
    for (int k=0;k<3;k++){
        const float* hb = h + (long)k*NROWS*HDIM + (long)row*HDIM;
        const float* wb = fc_w + k*HDIM;
        #pragma unroll
        for (int q=0;q<16;q++){
            v4 hv=*(const v4*)&hb[q*4];
            v4 wv=*(const v4*)&wb[q*4];
            acc += hv[0]*wv[0]+hv[1]*wv[1]+hv[2]*wv[2]+hv[3]*wv[3];
        }
    }
    x_cur[row]=acc;
    int b=row/NNODE, n=row-b*NNODE;
    out[((long)b*PRED + p)*NNODE + n] = acc;
}

extern "C" void kernel_launch(void* const* d_in, const int* in_sizes, int n_in,
                              void* d_out, int out_size, void* d_ws, size_t ws_size,
                              hipStream_t stream)
{
    const float* x_hist   = (const float*)d_in[0];
    const float* enc_misc = (const float*)d_in[1];
    const float* dec      = (const float*)d_in[2];
    const float* We       = (const float*)d_in[3];
    const float* be       = (const float*)d_in[4];
    const float* Wx       = (const float*)d_in[5];
    const float* Wh       = (const float*)d_in[6];
    const float* bx       = (const float*)d_in[7];
    const float* bh       = (const float*)d_in[8];
    const float* fc_w     = (const float*)d_in[9];
    const float* fc_b     = (const float*)d_in[10];
    const int*   src      = (const int*)d_in[11];
    const int*   dst      = (const int*)d_in[12];
    float* out = (float*)d_out;

    // ---- workspace layout (dynamic hist-batch chunk) ----
    const size_t SZ_T = (size_t)NROWS*FD;               // one (t) slice: 833,280 floats
    size_t fixed_f = (size_t)3*NROWS*HDIM + NROWS + 32*1024;  // h + x_cur + csr/slack
    size_t avail_f = ws_size/4;
    long tc = 1;
    if (avail_f > fixed_f + 4*SZ_T)
        tc = (long)((avail_f - fixed_f) / (4*SZ_T));
    if (tc > HIST-1) tc = HIST-1;
    if (tc < 1) tc = 1;
    const long T_CHUNK = tc;

    float* h      = (float*)d_ws;                       // 3*NROWS*HDIM
    float* x_cur  = h + (size_t)3*NROWS*HDIM;           // NROWS
    int*   deg    = (int*)(x_cur + NROWS);              // NNODE
    int*   offs   = deg + NNODE;                        // NNODE+1
    int*   curs   = offs + NNODE + 1;                   // NNODE
    int*   elist  = curs + NNODE;                       // NE
    float* xn_all = (float*)(elist + NE) + 16;          // T_CHUNK * SZ_T
    xn_all = (float*)(((size_t)xn_all + 63) & ~(size_t)63);
    float* xg_all = xn_all + T_CHUNK*SZ_T;              // 3 * T_CHUNK * SZ_T
    const long K_STRIDE = T_CHUNK*SZ_T;

    hipMemsetAsync(h, 0, (size_t)3*NROWS*HDIM*sizeof(float), stream);
    hipMemsetAsync(deg, 0, NNODE*sizeof(int), stream);

    const int gE = (NE+255)/256;
    csr_count_k<<<gE,256,0,stream>>>(dst, deg);
    csr_scan_k<<<1,1024,0,stream>>>(deg, offs, curs);
    csr_fill_k<<<gE,256,0,stream>>>(dst, curs, elist);

    const int gRow = (NROWS+255)/256;     // 272

    // ---------------- history phase (batched GNN, sequential GRU) ----------------
    for (int t0 = 0; t0 < HIST-1; t0 += (int)T_CHUNK){
        int T = min((int)T_CHUNK, HIST-1-t0);
        build_hist_k<<<(T*NROWS+255)/256,256,0,stream>>>(x_hist, enc_misc, t0, T, xn_all);
        dim3 gG(NB*8, T);
        gnn_gather_k<<<gG,256,0,stream>>>(xn_all,            We,be,src,dst,elist,offs, xg_all);
        gnn_gather_k<<<gG,256,0,stream>>>(xg_all,            We,be,src,dst,elist,offs, xg_all+K_STRIDE);
        gnn_gather_k<<<gG,256,0,stream>>>(xg_all+K_STRIDE,   We,be,src,dst,elist,offs, xg_all+2*K_STRIDE);
        for (int ti=0; ti<T; ti++){
            dim3 gU(NROWS/64, 3);
            gru3_k<<<gU,256,0,stream>>>(xg_all + ti*SZ_T, K_STRIDE,
                                        xn_all + ti*SZ_T, h, Wx, Wh, bx, bh);
        }
    }

    // ---------------- prediction phase (sequential) ----------------
    for (int p=0;p<PRED;p++){
        if (p==0)
            build_xn_k<<<gRow,256,0,stream>>>(x_hist,(long)HIST*NNODE,(long)(HIST-1)*NNODE,
                                              dec,(long)PRED*NNODE*FMD,(long)p*NNODE*FMD, xn_all);
        else
            build_xn_k<<<gRow,256,0,stream>>>(x_cur,(long)NNODE,0L,
                                              dec,(long)PRED*NNODE*FMD,(long)p*NNODE*FMD, xn_all);
        dim3 gG(NB*8, 1);
        gnn_gather_k<<<gG,256,0,stream>>>(xn_all,          We,be,src,dst,elist,offs, xg_all);
        gnn_gather_k<<<gG,256,0,stream>>>(xg_all,          We,be,src,dst,elist,offs, xg_all+K_STRIDE);
        gnn_gather_k<<<gG,256,0,stream>>>(xg_all+K_STRIDE, We,be,src,dst,elist,offs, xg_all+2*K_STRIDE);
        dim3 gU(NROWS/64, 3);
        gru3_k<<<gU,256,0,stream>>>(xg_all, K_STRIDE, xn_all, h, Wx, Wh, bx, bh);
        fc_k<<<gRow,256,0,stream>>>(h, fc_w, fc_b, x_cur, out, p);
    }
}